// Round 1
// baseline (396.582 us; speedup 1.0000x reference)
//
#include <hip/hip_runtime.h>
#include <math.h>

// LearnableSpectralHamiltonian: y = ifft2(fft2(x, ortho) * sqrt_lambda, ortho).real
// Filter is real & even in frequency -> real circular convolution.
// Pack two real images into one complex FFT: z = a + i*b; out_a = Re, out_b = Im.
// 64-pt FFT = two radix-8 stages; frequencies kept in digit-swapped order,
// filter is pre-permuted (kernel 1) so no reordering is ever done.
// All forward/inverse ortho scaling (1/4096) is folded into the filter.

#define ST 66  // LDS row stride in float2 units (== 2 mod 16)

__device__ __forceinline__ float2 cadd(float2 a, float2 b){ return make_float2(a.x+b.x, a.y+b.y); }
__device__ __forceinline__ float2 csub(float2 a, float2 b){ return make_float2(a.x-b.x, a.y-b.y); }
__device__ __forceinline__ float2 cmul(float2 a, float2 b){ return make_float2(a.x*b.x - a.y*b.y, a.x*b.y + a.y*b.x); }
__device__ __forceinline__ float2 cmulc(float2 a, float2 b){ // a * conj(b)
  return make_float2(a.x*b.x + a.y*b.y, a.y*b.x - a.x*b.y);
}

template<int SGN>  // SGN=-1 forward (e^{-i}), SGN=+1 inverse (e^{+i}), unscaled
__device__ __forceinline__ float2 crot(float2 a){  // multiply by SGN*i
  return (SGN < 0) ? make_float2(a.y, -a.x) : make_float2(-a.y, a.x);
}

template<int SGN>
__device__ __forceinline__ void fft8(float2 a[8]){
  const float s = 0.70710678118654752440f;
  float2 e0=a[0], e1=a[2], e2=a[4], e3=a[6];
  float2 o0=a[1], o1=a[3], o2=a[5], o3=a[7];
  float2 t0=cadd(e0,e2), t1=csub(e0,e2), t2=cadd(e1,e3), t3=crot<SGN>(csub(e1,e3));
  float2 E0=cadd(t0,t2), E2=csub(t0,t2), E1=cadd(t1,t3), E3=csub(t1,t3);
  float2 u0=cadd(o0,o2), u1=csub(o0,o2), u2=cadd(o1,o3), u3=crot<SGN>(csub(o1,o3));
  float2 O0=cadd(u0,u2), O2=csub(u0,u2), O1=cadd(u1,u3), O3=csub(u1,u3);
  const float2 w1 = make_float2( s, (SGN < 0) ? -s : s);
  const float2 w3 = make_float2(-s, (SGN < 0) ? -s : s);
  O1 = cmul(O1, w1);
  O2 = crot<SGN>(O2);
  O3 = cmul(O3, w3);
  a[0]=cadd(E0,O0); a[4]=csub(E0,O0);
  a[1]=cadd(E1,O1); a[5]=csub(E1,O1);
  a[2]=cadd(E2,O2); a[6]=csub(E2,O2);
  a[3]=cadd(E3,O3); a[7]=csub(E3,O3);
}

// compile-time-only ordering pin for intra-wave LDS producer/consumer phases
__device__ __forceinline__ void lds_sync(){
  __builtin_amdgcn_fence(__ATOMIC_ACQ_REL, "wavefront");
  __builtin_amdgcn_wave_barrier();
  __builtin_amdgcn_fence(__ATOMIC_ACQ_REL, "wavefront");
}

// ---------------------------------------------------------------------------
// Kernel 1: build permuted, pre-scaled sqrt(lambda). One block of 256 threads.
// Sperm[swap(h)*64 + swap(w)] = exp(0.5*(ellc - mean(ellc))) / 4096
// where swap(p) = ((p&7)<<3)|(p>>3)  (radix-8 digit swap).
// ---------------------------------------------------------------------------
__global__ void filter_kernel(const float* __restrict__ g1p,
                              const float* __restrict__ rawd,
                              const int*   __restrict__ bidx,
                              float*       __restrict__ Sperm){
  __shared__ float gsh[16];
  __shared__ float red[256];
  const int tid = threadIdx.x;
  if (tid == 0){
    float g = g1p[0];
    gsh[0] = g;
    for (int b = 0; b < 15; ++b){
      float d = rawd[b];
      float sp = (d > 20.f) ? d : log1pf(expf(d));  // softplus
      g += sp;
      gsh[b+1] = g;
    }
  }
  __syncthreads();
  float ell[16];
  float sacc = 0.f;
  #pragma unroll
  for (int i = 0; i < 16; ++i){
    int p = tid + 256*i;
    ell[i] = gsh[bidx[p]];
    sacc += ell[i];
  }
  red[tid] = sacc; __syncthreads();
  for (int off = 128; off > 0; off >>= 1){
    if (tid < off) red[tid] += red[tid + off];
    __syncthreads();
  }
  float mean1 = red[0] * (1.f/4096.f);
  __syncthreads();
  sacc = 0.f;
  #pragma unroll
  for (int i = 0; i < 16; ++i){
    float e = ell[i] - mean1;
    e = fminf(fmaxf(e, -3.f), 3.f);
    ell[i] = e;
    sacc += e;
  }
  red[tid] = sacc; __syncthreads();
  for (int off = 128; off > 0; off >>= 1){
    if (tid < off) red[tid] += red[tid + off];
    __syncthreads();
  }
  float mean2 = red[0] * (1.f/4096.f);
  #pragma unroll
  for (int i = 0; i < 16; ++i){
    int p = tid + 256*i;
    int h = p >> 6, w = p & 63;
    float val = expf(0.5f * (ell[i] - mean2)) * (1.0f/4096.0f);
    int ph = ((h & 7) << 3) | (h >> 3);
    int pw = ((w & 7) << 3) | (w >> 3);
    Sperm[ph*64 + pw] = val;
  }
}

// ---------------------------------------------------------------------------
// Kernel 2: one block per image PAIR. 512 threads, 64x64 complex tile in LDS.
// LDS address swizzle: addr(row a, col b) = a*ST + (b ^ (a & 15))
//   -> every access loop lands at the 4-lanes/bank-pair b64 floor.
// ---------------------------------------------------------------------------
__global__ __launch_bounds__(512) void spectral_kernel(
    const float* __restrict__ x, const float* __restrict__ Sp, float* __restrict__ y)
{
  __shared__ float2 tile[64*ST];
  __shared__ float2 twl[64];   // twl[n1*8+k2] = exp(-2*pi*i*n1*k2/64)
  const int tid = threadIdx.x;
  const long long baseA = (long long)blockIdx.x * 8192;
  const float* xA = x + baseA;
  const float* xB = xA + 4096;
  float* yA = y + baseA;
  float* yB = yA + 4096;

  if (tid < 64){
    int n1 = tid >> 3, k2 = tid & 7;
    float ang = -(float)M_PI * (float)(n1 * k2) / 32.0f;
    float sv, cv;
    __sincosf(ang, &sv, &cv);
    twl[tid] = make_float2(cv, sv);
  }

  // ---- load: z = a + i*b ----
  #pragma unroll
  for (int q = 0; q < 2; ++q){
    int f = tid + q*512;                  // float4 index in [0,1024)
    int row = f >> 4, g = (f & 15) << 2;  // col base
    float4 va = ((const float4*)xA)[f];
    float4 vb = ((const float4*)xB)[f];
    int m = row & 15, rb = row * ST;
    tile[rb + ((g+0) ^ m)] = make_float2(va.x, vb.x);
    tile[rb + ((g+1) ^ m)] = make_float2(va.y, vb.y);
    tile[rb + ((g+2) ^ m)] = make_float2(va.z, vb.z);
    tile[rb + ((g+3) ^ m)] = make_float2(va.w, vb.w);
  }
  __syncthreads();

  // ---- forward rows (two radix-8 stages) ----
  {
    const int r = tid >> 3, t = tid & 7;          // t = n1
    const int rb = r * ST, m = r & 15;
    float2 a[8];
    #pragma unroll
    for (int j = 0; j < 8; ++j) a[j] = tile[rb + ((t + 8*j) ^ m)];   // a[n2]
    fft8<-1>(a);                                                      // -> a[k2]
    #pragma unroll
    for (int j = 0; j < 8; ++j) a[j] = cmul(a[j], twl[t*8 + j]);
    lds_sync();
    #pragma unroll
    for (int j = 0; j < 8; ++j) tile[rb + ((8*t + j) ^ m)] = a[j];   // B at 8*n1+k2
    lds_sync();
  }
  {
    const int r = tid >> 3, t = tid & 7;          // t = k2
    const int rb = r * ST, m = r & 15;
    float2 a[8];
    #pragma unroll
    for (int j = 0; j < 8; ++j) a[j] = tile[rb + ((8*j + t) ^ m)];   // a[n1]
    fft8<-1>(a);                                                      // -> a[k1]
    lds_sync();
    #pragma unroll
    for (int j = 0; j < 8; ++j) tile[rb + ((8*t + j) ^ m)] = a[j];   // X[k2+8k1] at 8*k2+k1
  }
  __syncthreads();

  // ---- forward cols ----
  {
    const int c = tid >> 3, t = tid & 7;          // t = n1
    float2 a[8];
    #pragma unroll
    for (int j = 0; j < 8; ++j){ int i = t + 8*j; a[j] = tile[i*ST + (c ^ (i & 15))]; }
    fft8<-1>(a);
    #pragma unroll
    for (int j = 0; j < 8; ++j) a[j] = cmul(a[j], twl[t*8 + j]);
    lds_sync();
    #pragma unroll
    for (int j = 0; j < 8; ++j){ int i = 8*t + j; tile[i*ST + (c ^ (i & 15))] = a[j]; }
    lds_sync();
  }
  {
    const int c = tid >> 3, t = tid & 7;          // t = k2
    float2 a[8];
    #pragma unroll
    for (int j = 0; j < 8; ++j){ int i = 8*j + t; a[j] = tile[i*ST + (c ^ (i & 15))]; }
    fft8<-1>(a);
    lds_sync();
    #pragma unroll
    for (int j = 0; j < 8; ++j){ int i = 8*t + j; tile[i*ST + (c ^ (i & 15))] = a[j]; }
    lds_sync();
  }

  // ---- filter multiply fused with inverse cols ----
  {
    const int c = tid >> 3, t = tid & 7;          // t = k2
    float2 a[8];
    #pragma unroll
    for (int j = 0; j < 8; ++j){
      int i = 8*t + j;                            // k1 = j
      float sc = Sp[i*64 + c];
      float2 v = tile[i*ST + (c ^ (i & 15))];
      a[j] = make_float2(v.x*sc, v.y*sc);
    }
    fft8<+1>(a);                                  // -> a[n1]
    #pragma unroll
    for (int j = 0; j < 8; ++j) a[j] = cmulc(a[j], twl[j*8 + t]);   // * conj(w64^{n1*k2})
    lds_sync();
    #pragma unroll
    for (int j = 0; j < 8; ++j){ int i = t + 8*j; tile[i*ST + (c ^ (i & 15))] = a[j]; } // at k2+8n1
    lds_sync();
  }
  {
    const int c = tid >> 3, t = tid & 7;          // t = n1
    float2 a[8];
    #pragma unroll
    for (int j = 0; j < 8; ++j){ int i = j + 8*t; a[j] = tile[i*ST + (c ^ (i & 15))]; } // a[k2]
    fft8<+1>(a);                                  // -> a[n2]
    lds_sync();
    #pragma unroll
    for (int j = 0; j < 8; ++j){ int i = t + 8*j; tile[i*ST + (c ^ (i & 15))] = a[j]; } // x at n1+8n2
  }
  __syncthreads();

  // ---- inverse rows ----
  {
    const int r = tid >> 3, t = tid & 7;          // t = k2
    const int rb = r * ST, m = r & 15;
    float2 a[8];
    #pragma unroll
    for (int j = 0; j < 8; ++j) a[j] = tile[rb + ((8*t + j) ^ m)];   // a[k1]
    fft8<+1>(a);                                  // -> a[n1]
    #pragma unroll
    for (int j = 0; j < 8; ++j) a[j] = cmulc(a[j], twl[j*8 + t]);
    lds_sync();
    #pragma unroll
    for (int j = 0; j < 8; ++j) tile[rb + ((t + 8*j) ^ m)] = a[j];   // at k2+8n1
    lds_sync();
  }
  {
    const int r = tid >> 3, t = tid & 7;          // t = n1
    const int rb = r * ST, m = r & 15;
    float2 a[8];
    #pragma unroll
    for (int j = 0; j < 8; ++j) a[j] = tile[rb + ((j + 8*t) ^ m)];   // a[k2]
    fft8<+1>(a);                                  // -> a[n2]
    lds_sync();
    #pragma unroll
    for (int j = 0; j < 8; ++j) tile[rb + ((t + 8*j) ^ m)] = a[j];   // x at n1+8n2
  }
  __syncthreads();

  // ---- store: Re -> image A, Im -> image B ----
  #pragma unroll
  for (int q = 0; q < 2; ++q){
    int f = tid + q*512;
    int row = f >> 4, g = (f & 15) << 2;
    int m = row & 15, rb = row * ST;
    float2 v0 = tile[rb + ((g+0) ^ m)];
    float2 v1 = tile[rb + ((g+1) ^ m)];
    float2 v2 = tile[rb + ((g+2) ^ m)];
    float2 v3 = tile[rb + ((g+3) ^ m)];
    ((float4*)yA)[f] = make_float4(v0.x, v1.x, v2.x, v3.x);
    ((float4*)yB)[f] = make_float4(v0.y, v1.y, v2.y, v3.y);
  }
}

extern "C" void kernel_launch(void* const* d_in, const int* in_sizes, int n_in,
                              void* d_out, int out_size, void* d_ws, size_t ws_size,
                              hipStream_t stream){
  (void)in_sizes; (void)n_in; (void)out_size; (void)ws_size;
  const float* x    = (const float*)d_in[0];
  const float* g1   = (const float*)d_in[1];
  const float* rawd = (const float*)d_in[2];
  const int*   bidx = (const int*)d_in[3];
  float* y     = (float*)d_out;
  float* Sperm = (float*)d_ws;   // 4096 floats

  filter_kernel<<<dim3(1), dim3(256), 0, stream>>>(g1, rawd, bidx, Sperm);
  spectral_kernel<<<dim3(6144), dim3(512), 0, stream>>>(x, Sperm, y);
}

// Round 2
// 360.669 us; speedup vs baseline: 1.0996x; 1.0996x over previous
//
#include <hip/hip_runtime.h>
#include <math.h>

// y = ifft2(fft2(x, ortho) * sqrt_lambda, ortho).real ; filter real+even ->
// pack two real images as z = a + i*b, out_a = Re, out_b = Im.
// 64-pt FFT = radix-8 x radix-8; ONE lane-transpose per 1-D FFT, done through
// the wave's own tile cells (conflict-free b128 write / b64 read patterns).
// Frequencies kept digit-swapped in the column dim; filter pre-permuted.
// All ortho scaling (1/4096) folded into the filter.

__device__ __forceinline__ float2 cadd(float2 a, float2 b){ return make_float2(a.x+b.x, a.y+b.y); }
__device__ __forceinline__ float2 csub(float2 a, float2 b){ return make_float2(a.x-b.x, a.y-b.y); }
__device__ __forceinline__ float2 cmul(float2 a, float2 b){ return make_float2(a.x*b.x - a.y*b.y, a.x*b.y + a.y*b.x); }
__device__ __forceinline__ float2 cmulc(float2 a, float2 b){ // a * conj(b)
  return make_float2(a.x*b.x + a.y*b.y, a.y*b.x - a.x*b.y);
}

template<int SGN>
__device__ __forceinline__ float2 crot(float2 a){  // multiply by SGN*i
  return (SGN < 0) ? make_float2(a.y, -a.x) : make_float2(-a.y, a.x);
}

template<int SGN>
__device__ __forceinline__ void fft8(float2 a[8]){
  const float s = 0.70710678118654752440f;
  float2 e0=a[0], e1=a[2], e2=a[4], e3=a[6];
  float2 o0=a[1], o1=a[3], o2=a[5], o3=a[7];
  float2 t0=cadd(e0,e2), t1=csub(e0,e2), t2=cadd(e1,e3), t3=crot<SGN>(csub(e1,e3));
  float2 E0=cadd(t0,t2), E2=csub(t0,t2), E1=cadd(t1,t3), E3=csub(t1,t3);
  float2 u0=cadd(o0,o2), u1=csub(o0,o2), u2=cadd(o1,o3), u3=crot<SGN>(csub(o1,o3));
  float2 O0=cadd(u0,u2), O2=csub(u0,u2), O1=cadd(u1,u3), O3=csub(u1,u3);
  const float2 w1 = make_float2( s, (SGN < 0) ? -s : s);
  const float2 w3 = make_float2(-s, (SGN < 0) ? -s : s);
  O1 = cmul(O1, w1);
  O2 = crot<SGN>(O2);
  O3 = cmul(O3, w3);
  a[0]=cadd(E0,O0); a[4]=csub(E0,O0);
  a[1]=cadd(E1,O1); a[5]=csub(E1,O1);
  a[2]=cadd(E2,O2); a[6]=csub(E2,O2);
  a[3]=cadd(E3,O3); a[7]=csub(E3,O3);
}

// intra-wave LDS producer/consumer ordering pin (DS pipe is in-order per wave)
__device__ __forceinline__ void lds_sync(){
  __builtin_amdgcn_fence(__ATOMIC_ACQ_REL, "wavefront");
  __builtin_amdgcn_wave_barrier();
  __builtin_amdgcn_fence(__ATOMIC_ACQ_REL, "wavefront");
}

// ---------------------------------------------------------------------------
// Kernel 1: permuted, pre-scaled sqrt(lambda). One block of 256 threads.
// Fperm[kr*64 + c] = F[kr][swap(c)], swap(8a+b)=8b+a (column digit-swap only).
// ---------------------------------------------------------------------------
__global__ void filter_kernel(const float* __restrict__ g1p,
                              const float* __restrict__ rawd,
                              const int*   __restrict__ bidx,
                              float*       __restrict__ Sperm){
  __shared__ float gsh[16];
  __shared__ float red[256];
  const int tid = threadIdx.x;
  if (tid == 0){
    float g = g1p[0];
    gsh[0] = g;
    for (int b = 0; b < 15; ++b){
      float d = rawd[b];
      float sp = (d > 20.f) ? d : log1pf(expf(d));  // softplus
      g += sp;
      gsh[b+1] = g;
    }
  }
  __syncthreads();
  float ell[16];
  float sacc = 0.f;
  #pragma unroll
  for (int i = 0; i < 16; ++i){
    int p = tid + 256*i;
    ell[i] = gsh[bidx[p]];
    sacc += ell[i];
  }
  red[tid] = sacc; __syncthreads();
  for (int off = 128; off > 0; off >>= 1){
    if (tid < off) red[tid] += red[tid + off];
    __syncthreads();
  }
  float mean1 = red[0] * (1.f/4096.f);
  __syncthreads();
  sacc = 0.f;
  #pragma unroll
  for (int i = 0; i < 16; ++i){
    float e = ell[i] - mean1;
    e = fminf(fmaxf(e, -3.f), 3.f);
    ell[i] = e;
    sacc += e;
  }
  red[tid] = sacc; __syncthreads();
  for (int off = 128; off > 0; off >>= 1){
    if (tid < off) red[tid] += red[tid + off];
    __syncthreads();
  }
  float mean2 = red[0] * (1.f/4096.f);
  #pragma unroll
  for (int i = 0; i < 16; ++i){
    int p = tid + 256*i;
    int h = p >> 6, w = p & 63;
    float val = expf(0.5f * (ell[i] - mean2)) * (1.0f/4096.0f);
    int pw = ((w & 7) << 3) | (w >> 3);      // column digit-swap only
    Sperm[h*64 + pw] = val;
  }
}

// ---------------------------------------------------------------------------
// Kernel 2: one block per image PAIR. 512 threads, 64x66 float2 tile.
// ---------------------------------------------------------------------------
__global__ __launch_bounds__(512, 4) void spectral_kernel(
    const float* __restrict__ x, const float* __restrict__ Sp, float* __restrict__ y)
{
  __shared__ float2 tile[64*66];
  float4* tile4 = reinterpret_cast<float4*>(tile);
  const int tid = threadIdx.x;
  const int g = tid >> 3;           // row (A/C) or column (B)
  const int t = tid & 7;            // digit lane within the 8-thread group
  const long long baseA = (long long)blockIdx.x * 8192;
  const float* xA = x + baseA;
  const float* xB = xA + 4096;
  float* yA = y + baseA;
  float* yB = yA + 4096;

  // per-thread twiddles: tw[j] = exp(-i*2*pi*t*j/64); symmetric, inverse=conj
  float2 tw[8];
  #pragma unroll
  for (int j = 0; j < 8; ++j){
    float sv, cv;
    __sincosf(-(float)M_PI * (float)(t*j) / 32.0f, &sv, &cv);
    tw[j] = make_float2(cv, sv);
  }

  // ================= Phase A: load + forward row FFT =================
  {
    const float* rA = xA + (g << 6);
    const float* rB = xB + (g << 6);
    float2 a[8];
    #pragma unroll
    for (int j = 0; j < 8; ++j) a[j] = make_float2(rA[t + 8*j], rB[t + 8*j]);  // n1=t, regs=n2
    fft8<-1>(a);                                    // -> k2
    #pragma unroll
    for (int j = 1; j < 8; ++j) a[j] = cmul(a[j], tw[j]);   // w64^{n1*k2}
    // transpose among the row's 8 lanes via the wave's own rows
    #pragma unroll
    for (int q = 0; q < 4; ++q)
      tile4[33*g + 4*t + q] = make_float4(a[2*q].x, a[2*q].y, a[2*q+1].x, a[2*q+1].y);
    lds_sync();
    #pragma unroll
    for (int j = 0; j < 8; ++j) a[j] = tile[66*g + 8*j + t];   // thread=k2, regs=n1
    fft8<-1>(a);                                    // -> k1
    lds_sync();
    #pragma unroll
    for (int q = 0; q < 4; ++q)   // logical col s = 8t+j holds X[t+8j]
      tile4[33*g + 4*t + q] = make_float4(a[2*q].x, a[2*q].y, a[2*q+1].x, a[2*q+1].y);
  }
  __syncthreads();

  // ========== Phase B: column FFT + filter + inverse column FFT ==========
  {
    const int c = g;                // this thread's column
    const int d = c & 7, Wv = c >> 3;
    float2 a[8];
    #pragma unroll
    for (int j = 0; j < 8; ++j) a[j] = tile[66*(t + 8*j) + c];   // n1=t, regs=n2
    fft8<-1>(a);                                    // -> k2
    #pragma unroll
    for (int j = 1; j < 8; ++j) a[j] = cmul(a[j], tw[j]);
    lds_sync();
    #pragma unroll
    for (int q = 0; q < 4; ++q)     // scratch = the wave's own 8 columns
      tile4[33*(8*t + d) + 4*Wv + q] = make_float4(a[2*q].x, a[2*q].y, a[2*q+1].x, a[2*q+1].y);
    lds_sync();
    #pragma unroll
    for (int j = 0; j < 8; ++j) a[j] = tile[66*(8*j + d) + 8*Wv + t];  // thread=k2, regs=n1
    fft8<-1>(a);                                    // -> k1 ; k_row = t + 8j
    #pragma unroll
    for (int j = 0; j < 8; ++j){
      float f = Sp[((t + 8*j) << 6) + c];
      a[j].x *= f; a[j].y *= f;
    }
    fft8<+1>(a);                                    // k1 -> n1
    #pragma unroll
    for (int j = 1; j < 8; ++j) a[j] = cmulc(a[j], tw[j]);   // conj(w64^{n1*k2})
    lds_sync();
    #pragma unroll
    for (int q = 0; q < 4; ++q)
      tile4[33*(8*t + d) + 4*Wv + q] = make_float4(a[2*q].x, a[2*q].y, a[2*q+1].x, a[2*q+1].y);
    lds_sync();
    #pragma unroll
    for (int j = 0; j < 8; ++j) a[j] = tile[66*(8*j + d) + 8*Wv + t];  // thread=n1, regs=k2
    fft8<+1>(a);                                    // -> n2
    lds_sync();
    #pragma unroll
    for (int j = 0; j < 8; ++j) tile[66*(t + 8*j) + c] = a[j];   // spatial rows t+8j
  }
  __syncthreads();

  // ================= Phase C: inverse row FFT + store =================
  {
    float2 a[8];
    #pragma unroll
    for (int q = 0; q < 4; ++q){
      float4 v = tile4[33*g + 4*t + q];             // cols 8t+j hold k = t+8j
      a[2*q]   = make_float2(v.x, v.y);
      a[2*q+1] = make_float2(v.z, v.w);
    }
    fft8<+1>(a);                                    // k1 -> n1
    #pragma unroll
    for (int j = 1; j < 8; ++j) a[j] = cmulc(a[j], tw[j]);
    lds_sync();
    #pragma unroll
    for (int q = 0; q < 4; ++q)
      tile4[33*g + 4*t + q] = make_float4(a[2*q].x, a[2*q].y, a[2*q+1].x, a[2*q+1].y);
    lds_sync();
    #pragma unroll
    for (int j = 0; j < 8; ++j) a[j] = tile[66*g + 8*j + t];   // thread=n1, regs=k2
    fft8<+1>(a);                                    // -> n2 ; holds x[t + 8j]
    float* wA = yA + (g << 6) + t;
    float* wB = yB + (g << 6) + t;
    #pragma unroll
    for (int j = 0; j < 8; ++j){ wA[8*j] = a[j].x; wB[8*j] = a[j].y; }
  }
}

extern "C" void kernel_launch(void* const* d_in, const int* in_sizes, int n_in,
                              void* d_out, int out_size, void* d_ws, size_t ws_size,
                              hipStream_t stream){
  (void)in_sizes; (void)n_in; (void)out_size; (void)ws_size;
  const float* x    = (const float*)d_in[0];
  const float* g1   = (const float*)d_in[1];
  const float* rawd = (const float*)d_in[2];
  const int*   bidx = (const int*)d_in[3];
  float* y     = (float*)d_out;
  float* Sperm = (float*)d_ws;   // 4096 floats

  filter_kernel<<<dim3(1), dim3(256), 0, stream>>>(g1, rawd, bidx, Sperm);
  spectral_kernel<<<dim3(6144), dim3(512), 0, stream>>>(x, Sperm, y);
}